// Round 16
// baseline (6307.528 us; speedup 1.0000x reference)
//
#include <hip/hip_runtime.h>

#define LOG2E 1.44269504088896340736f

__device__ __forceinline__ float lrelu(float z) { return fmaxf(z, 0.01f * z); }
__device__ __forceinline__ float sigf(float z) {
    float p = __builtin_amdgcn_exp2f(-LOG2E * z);
    return __builtin_amdgcn_rcpf(1.0f + p);
}

// ============ Prep: pack all weights into d_ws in consumption order ==========
// Float layout (2528 floats = 10112 B):
//  F: [0)    trip j: {Wh1[j], Wh1[50+j], bh1[j], 0} x50      (200 floats)
//     [200)  Wh2 row-major [50][20]                           (1000)
//     [1200) bh2 (20) | [1220) Wh3 [20][2] (40) | [1260) bh3 (2) + pad
//  G: [1264) trip {Wx1...} | [1464) Wx2 | [2464) bx2 | [2484) Wx3 | [2524) bx3
__global__ void pack_kernel(const float* __restrict__ Wh1, const float* __restrict__ bh1,
                            const float* __restrict__ Wh2, const float* __restrict__ bh2,
                            const float* __restrict__ Wh3, const float* __restrict__ bh3,
                            const float* __restrict__ Wx1, const float* __restrict__ bx1,
                            const float* __restrict__ Wx2, const float* __restrict__ bx2,
                            const float* __restrict__ Wx3, const float* __restrict__ bx3,
                            float* __restrict__ wp)
{
    const int tid = threadIdx.x;
    for (int j = tid; j < 50; j += 256) {
        wp[4*j+0] = Wh1[j]; wp[4*j+1] = Wh1[50+j]; wp[4*j+2] = bh1[j]; wp[4*j+3] = 0.f;
        wp[1264+4*j+0] = Wx1[j]; wp[1264+4*j+1] = Wx1[50+j]; wp[1264+4*j+2] = bx1[j]; wp[1264+4*j+3] = 0.f;
    }
    for (int i = tid; i < 1000; i += 256) { wp[200+i] = Wh2[i]; wp[1464+i] = Wx2[i]; }
    if (tid < 20) { wp[1200+tid] = bh2[tid]; wp[2464+tid] = bx2[tid]; }
    if (tid < 40) { wp[1220+tid] = Wh3[tid]; wp[2484+tid] = Wx3[tid]; }
    if (tid < 2)  { wp[1260+tid] = bh3[tid]; wp[2524+tid] = bx3[tid]; }
    if (tid >= 2 && tid < 4) { wp[1260+tid] = 0.f; wp[2524+tid] = 0.f; }
}

// ============ Fused recurrence, weights via SMEM (s_load) ====================
// R15 evidence: v_readlane issues at ~8 cyc (quarter rate) — broadcasts were
// the bottleneck in R10-R15 (model fits all five rounds). SMEM weight reads
// (uniform s_load_dwordx4+, single base pointer, ordered compile-time offsets)
// cost ZERO VALU and no LDS. ILP restructure: per iteration both F(h_t) and
// G(h_t)=x_{t-1} depend only on h_t -> two independent ~1400-instr chains.
// float4 indices into wp: F trip j | F W2 50+5k+c4 | F b2 300+c4 |
// F W3 305+p | F b3 315 | G trip 316+j | G W2 366+5k+c4 | G b2 616+c4 |
// G W3 621+p | G b3 631
__global__ void __launch_bounds__(256, 1)
fused_smem_kernel(const float* __restrict__ w, const float4* __restrict__ wp,
                  float2* __restrict__ out, int B, int T)
{
    const int bidx = blockIdx.x * blockDim.x + threadIdx.x;
    float h0 = w[2 * bidx], h1 = w[2 * bidx + 1];
    float2* __restrict__ orow = out + (size_t)bidx * (size_t)T;

    // t = 0..T: at t<T compute h_{t+1}=F(h_t); at t>0 store x_{t-1}=G(h_t).
    for (int t = 0; t <= T; ++t) {
        const float hp0 = h0, hp1 = h1;   // h_t feeds BOTH chains

        // ======== chain F: h_{t+1} = lrelu3(h_t) ========
        if (t < T) {
            float a1[50];
#pragma unroll
            for (int j = 0; j < 50; ++j) {
                const float4 v = wp[j];
                a1[j] = lrelu(fmaf(hp0, v.x, fmaf(hp1, v.y, v.z)));
            }
            float acc[20];
#pragma unroll
            for (int c4 = 0; c4 < 5; ++c4) {
                const float4 b = wp[300 + c4];
                acc[4*c4+0] = b.x; acc[4*c4+1] = b.y; acc[4*c4+2] = b.z; acc[4*c4+3] = b.w;
            }
#pragma unroll
            for (int k = 0; k < 50; ++k) {
                const float ak = a1[k];
#pragma unroll
                for (int c4 = 0; c4 < 5; ++c4) {
                    const float4 v = wp[50 + k*5 + c4];
                    acc[4*c4+0] = fmaf(ak, v.x, acc[4*c4+0]);
                    acc[4*c4+1] = fmaf(ak, v.y, acc[4*c4+1]);
                    acc[4*c4+2] = fmaf(ak, v.z, acc[4*c4+2]);
                    acc[4*c4+3] = fmaf(ak, v.w, acc[4*c4+3]);
                }
            }
            const float4 b3v = wp[315];
            float z0 = b3v.x, z1 = b3v.y;
#pragma unroll
            for (int p = 0; p < 10; ++p) {
                const float4 v = wp[305 + p];
                const float e0 = lrelu(acc[2*p+0]);
                const float e1 = lrelu(acc[2*p+1]);
                z0 = fmaf(e0, v.x, fmaf(e1, v.z, z0));
                z1 = fmaf(e0, v.y, fmaf(e1, v.w, z1));
            }
            h0 = lrelu(z0); h1 = lrelu(z1);
        }

        // ======== chain G: x_{t-1} = sig3(h_t), independent of F ========
        {
            float x1[50];
#pragma unroll
            for (int j = 0; j < 50; ++j) {
                const float4 v = wp[316 + j];
                x1[j] = sigf(fmaf(hp0, v.x, fmaf(hp1, v.y, v.z)));
            }
            float accx[20];
#pragma unroll
            for (int c4 = 0; c4 < 5; ++c4) {
                const float4 b = wp[616 + c4];
                accx[4*c4+0] = b.x; accx[4*c4+1] = b.y; accx[4*c4+2] = b.z; accx[4*c4+3] = b.w;
            }
#pragma unroll
            for (int k = 0; k < 50; ++k) {
                const float xk = x1[k];
#pragma unroll
                for (int c4 = 0; c4 < 5; ++c4) {
                    const float4 v = wp[366 + k*5 + c4];
                    accx[4*c4+0] = fmaf(xk, v.x, accx[4*c4+0]);
                    accx[4*c4+1] = fmaf(xk, v.y, accx[4*c4+1]);
                    accx[4*c4+2] = fmaf(xk, v.z, accx[4*c4+2]);
                    accx[4*c4+3] = fmaf(xk, v.w, accx[4*c4+3]);
                }
            }
            const float4 b3x = wp[631];
            float zx0 = b3x.x, zx1 = b3x.y;
#pragma unroll
            for (int p = 0; p < 10; ++p) {
                const float4 v = wp[621 + p];
                const float e0 = sigf(accx[2*p+0]);
                const float e1 = sigf(accx[2*p+1]);
                zx0 = fmaf(e0, v.x, fmaf(e1, v.z, zx0));
                zx1 = fmaf(e0, v.y, fmaf(e1, v.w, zx1));
            }
            if (t > 0) orow[t-1] = make_float2(sigf(zx0), sigf(zx1));
        }
    }
}

extern "C" void kernel_launch(void* const* d_in, const int* in_sizes, int n_in,
                              void* d_out, int out_size, void* d_ws, size_t ws_size,
                              hipStream_t stream)
{
    const float* w   = (const float*)d_in[0];
    const float* Wh1 = (const float*)d_in[1];
    const float* bh1 = (const float*)d_in[2];
    const float* Wh2 = (const float*)d_in[3];
    const float* bh2 = (const float*)d_in[4];
    const float* Wh3 = (const float*)d_in[5];
    const float* bh3 = (const float*)d_in[6];
    const float* Wx1 = (const float*)d_in[7];
    const float* bx1 = (const float*)d_in[8];
    const float* Wx2 = (const float*)d_in[9];
    const float* bx2 = (const float*)d_in[10];
    const float* Wx3 = (const float*)d_in[11];
    const float* bx3 = (const float*)d_in[12];

    const int B = in_sizes[0] / 2;        // 65536
    const int T = out_size / (B * 2);     // 512

    float* wp = (float*)d_ws;             // needs 10112 B of scratch

    pack_kernel<<<1, 256, 0, stream>>>(
        Wh1, bh1, Wh2, bh2, Wh3, bh3,
        Wx1, bx1, Wx2, bx2, Wx3, bx3, wp);

    fused_smem_kernel<<<B / 256, 256, 0, stream>>>(
        w, (const float4*)wp, (float2*)d_out, B, T);
}

// Round 17
// 6302.327 us; speedup vs baseline: 1.0008x; 1.0008x over previous
//
#include <hip/hip_runtime.h>

#define LOG2E 1.44269504088896340736f

__device__ __forceinline__ float lrelu(float z) { return fmaxf(z, 0.01f * z); }
__device__ __forceinline__ float sigf(float z) {
    float p = __builtin_amdgcn_exp2f(-LOG2E * z);
    return __builtin_amdgcn_rcpf(1.0f + p);
}

// Broadcast weight (i) from the lane-distributed register file (compile-time
// reg/lane after unroll): v_readlane_b32 -> SGPR -> scalar operand of v_fma.
#define WQ(i) __int_as_float(__builtin_amdgcn_readlane(__float_as_int(wreg[(i) >> 6]), (i) & 63))

// =================== Phase 1: recurrent h-path ===================
// Validated pipe model (R10-R16): readlane = 8 cyc/float on the per-SIMD VALU;
// uniform ds_read_b128 = 12 cyc/4 floats on the per-CU LDS pipe (x4 waves/CU);
// fma = 2 cyc. Balance max(VALU, LDS): 2570 + 8R = 12(1212-R) -> R ~= 599.
// readlane pack R=592: 0..99 Wh1 | 100..149 bh1 | 150..529 Wh2 rows 31..49
//                      | 530..549 bh2 | 550..589 Wh3 | 590..591 bh3
// LDS: Wh2 rows 0..30 (620 floats, 155 float4).
__global__ void __launch_bounds__(256, 1)
hpath_kernel(const float* __restrict__ w,
             const float* __restrict__ Wh1, const float* __restrict__ bh1,
             const float* __restrict__ Wh2, const float* __restrict__ bh2,
             const float* __restrict__ Wh3, const float* __restrict__ bh3,
             float2* __restrict__ out, int B, int T)
{
    __shared__ float4 sW2[155];   // Wh2 rows 0..30, row k at [5k..5k+4]
    {
        float* s2 = (float*)sW2;
        for (int i = threadIdx.x; i < 620; i += 256) s2[i] = Wh2[i];
    }

    const int lane = threadIdx.x & 63;
    float wreg[10];
#pragma unroll
    for (int r = 0; r < 10; ++r) {
        const int idx = r * 64 + lane;
        float v = 0.f;
        if      (idx < 100) v = Wh1[idx];
        else if (idx < 150) v = bh1[idx - 100];
        else if (idx < 530) v = Wh2[620 + (idx - 150)];   // rows 31..49
        else if (idx < 550) v = bh2[idx - 530];
        else if (idx < 590) v = Wh3[idx - 550];
        else if (idx < 592) v = bh3[idx - 590];
        wreg[r] = v;
    }
    __syncthreads();

    const int bidx = blockIdx.x * blockDim.x + threadIdx.x;
    if (bidx >= B) return;   // B % 256 == 0: never taken

    float h0 = w[2 * bidx], h1 = w[2 * bidx + 1];
    float2* __restrict__ orow = out + (size_t)bidx * (size_t)T;

    for (int t = 0; t < T; ++t) {
        // ---- 2 -> 50, lrelu (readlane) ----
        float a1[50];
#pragma unroll
        for (int j = 0; j < 50; ++j)
            a1[j] = lrelu(fmaf(h0, WQ(j), fmaf(h1, WQ(50 + j), WQ(100 + j))));

        // ---- 50 -> 20 accumulate ----
        float acc[20];
#pragma unroll
        for (int c = 0; c < 20; ++c) acc[c] = WQ(530 + c);

#pragma unroll
        for (int k = 0; k < 31; ++k) {          // rows 0..30 via LDS
            const float ak = a1[k];
#pragma unroll
            for (int c = 0; c < 5; ++c) {
                const float4 v = sW2[k * 5 + c];
                acc[4*c+0] = fmaf(ak, v.x, acc[4*c+0]);
                acc[4*c+1] = fmaf(ak, v.y, acc[4*c+1]);
                acc[4*c+2] = fmaf(ak, v.z, acc[4*c+2]);
                acc[4*c+3] = fmaf(ak, v.w, acc[4*c+3]);
            }
        }
#pragma unroll
        for (int k = 31; k < 50; ++k) {         // rows 31..49 via readlane
            const float ak = a1[k];
#pragma unroll
            for (int c = 0; c < 20; ++c)
                acc[c] = fmaf(ak, WQ(150 + (k - 31) * 20 + c), acc[c]);
        }

        // ---- 20 -> 2, lrelu ----
        float z0 = WQ(590), z1 = WQ(591);
#pragma unroll
        for (int k = 0; k < 20; ++k) {
            const float a2k = lrelu(acc[k]);
            z0 = fmaf(a2k, WQ(550 + 2 * k + 0), z0);
            z1 = fmaf(a2k, WQ(550 + 2 * k + 1), z1);
        }
        h0 = lrelu(z0); h1 = lrelu(z1);
        orow[t] = make_float2(h0, h1);
    }
}

// =================== Phase 2: x = G(h), in place, 4 points/thread ===========
// R6 body verbatim (absmax 0 proven); only change: __launch_bounds__(256,3)
// to force >=3 waves/SIMD (VGPR cap ~170; R6 used 176 at 1 wave/SIMD and its
// 2.06ms was latency exposure, not pipe saturation: VALU 0.67ms / LDS 0.81ms).
__global__ void __launch_bounds__(256, 3)
xpath_kernel(const float* __restrict__ Wx1, const float* __restrict__ bx1,
             const float* __restrict__ Wx2, const float* __restrict__ bx2,
             const float* __restrict__ Wx3, const float* __restrict__ bx3,
             float2* __restrict__ out, int NG)   // NG = NP/4 four-point groups
{
    __shared__ float4 sL1[50];   // (W1[0][k], W1[1][k], b1[k], 0)
    __shared__ float4 sW2[250];  // W2[50][20] row-major; row k at [5k..5k+4]
    __shared__ float4 sW3[10];   // (W3[2q][0], W3[2q][1], W3[2q+1][0], W3[2q+1][1])
    __shared__ float4 sB2[5];
    __shared__ float2 sB3;
    {
        const int tid = threadIdx.x;
        if (tid < 50) sL1[tid] = make_float4(Wx1[tid], Wx1[50 + tid], bx1[tid], 0.f);
        float* s2 = (float*)sW2;
        for (int i = tid; i < 1000; i += 256) s2[i] = Wx2[i];
        if (tid < 40) ((float*)sW3)[tid] = Wx3[tid];
        if (tid < 20) ((float*)sB2)[tid] = bx2[tid];
        if (tid == 0) sB3 = make_float2(bx3[0], bx3[1]);
    }
    __syncthreads();

    const int stride = gridDim.x * blockDim.x;
    for (int g = blockIdx.x * blockDim.x + threadIdx.x; g < NG; g += stride) {
        const float4 hv01 = reinterpret_cast<const float4*>(out)[2 * g];
        const float4 hv23 = reinterpret_cast<const float4*>(out)[2 * g + 1];
        const float h0[4] = {hv01.x, hv01.z, hv23.x, hv23.z};
        const float h1[4] = {hv01.y, hv01.w, hv23.y, hv23.w};

        float acc[4][20];
#pragma unroll
        for (int c4 = 0; c4 < 5; ++c4) {
            const float4 b = sB2[c4];
#pragma unroll
            for (int p = 0; p < 4; ++p) {
                acc[p][4 * c4 + 0] = b.x; acc[p][4 * c4 + 1] = b.y;
                acc[p][4 * c4 + 2] = b.z; acc[p][4 * c4 + 3] = b.w;
            }
        }
        // layers 1+2 fused over k
#pragma unroll
        for (int k = 0; k < 50; ++k) {
            const float4 l1 = sL1[k];
            float xk[4];
#pragma unroll
            for (int p = 0; p < 4; ++p)
                xk[p] = sigf(fmaf(h0[p], l1.x, fmaf(h1[p], l1.y, l1.z)));
#pragma unroll
            for (int c4 = 0; c4 < 5; ++c4) {
                const float4 v = sW2[k * 5 + c4];
#pragma unroll
                for (int p = 0; p < 4; ++p) {
                    acc[p][4 * c4 + 0] = fmaf(xk[p], v.x, acc[p][4 * c4 + 0]);
                    acc[p][4 * c4 + 1] = fmaf(xk[p], v.y, acc[p][4 * c4 + 1]);
                    acc[p][4 * c4 + 2] = fmaf(xk[p], v.z, acc[p][4 * c4 + 2]);
                    acc[p][4 * c4 + 3] = fmaf(xk[p], v.w, acc[p][4 * c4 + 3]);
                }
            }
        }
        // layer 3 (sigmoid of acc fused into the dot)
        const float2 b3 = sB3;
        float z0[4], z1[4];
#pragma unroll
        for (int p = 0; p < 4; ++p) { z0[p] = b3.x; z1[p] = b3.y; }
#pragma unroll
        for (int q = 0; q < 10; ++q) {
            const float4 v = sW3[q];
#pragma unroll
            for (int p = 0; p < 4; ++p) {
                const float x2a = sigf(acc[p][2 * q + 0]);
                const float x2b = sigf(acc[p][2 * q + 1]);
                z0[p] = fmaf(x2a, v.x, z0[p]); z1[p] = fmaf(x2a, v.y, z1[p]);
                z0[p] = fmaf(x2b, v.z, z0[p]); z1[p] = fmaf(x2b, v.w, z1[p]);
            }
        }
        const float4 o01 = make_float4(sigf(z0[0]), sigf(z1[0]), sigf(z0[1]), sigf(z1[1]));
        const float4 o23 = make_float4(sigf(z0[2]), sigf(z1[2]), sigf(z0[3]), sigf(z1[3]));
        reinterpret_cast<float4*>(out)[2 * g]     = o01;
        reinterpret_cast<float4*>(out)[2 * g + 1] = o23;
    }
}

extern "C" void kernel_launch(void* const* d_in, const int* in_sizes, int n_in,
                              void* d_out, int out_size, void* d_ws, size_t ws_size,
                              hipStream_t stream)
{
    const float* w   = (const float*)d_in[0];
    const float* Wh1 = (const float*)d_in[1];
    const float* bh1 = (const float*)d_in[2];
    const float* Wh2 = (const float*)d_in[3];
    const float* bh2 = (const float*)d_in[4];
    const float* Wh3 = (const float*)d_in[5];
    const float* bh3 = (const float*)d_in[6];
    const float* Wx1 = (const float*)d_in[7];
    const float* bx1 = (const float*)d_in[8];
    const float* Wx2 = (const float*)d_in[9];
    const float* bx2 = (const float*)d_in[10];
    const float* Wx3 = (const float*)d_in[11];
    const float* bx3 = (const float*)d_in[12];

    const int B  = in_sizes[0] / 2;        // 65536
    const int T  = out_size / (B * 2);     // 512
    const int NP = B * T;                  // 33.5M (b,t) points; divisible by 4
    const int NG = NP / 4;

    float2* out2 = (float2*)d_out;

    // Phase 1: recurrent h-path (balanced LDS/readlane split, R~=599).
    hpath_kernel<<<(B + 255) / 256, 256, 0, stream>>>(
        w, Wh1, bh1, Wh2, bh2, Wh3, bh3, out2, B, T);

    // Phase 2: x = G(h) in place, 4 points/thread, >=3 waves/SIMD.
    xpath_kernel<<<4096, 256, 0, stream>>>(
        Wx1, bx1, Wx2, bx2, Wx3, bx3, out2, NG);
}

// Round 18
// 5215.923 us; speedup vs baseline: 1.2093x; 1.2083x over previous
//
#include <hip/hip_runtime.h>

#define LOG2E 1.44269504088896340736f

__device__ __forceinline__ float lrelu(float z) { return fmaxf(z, 0.01f * z); }
__device__ __forceinline__ float sigf(float z) {
    float p = __builtin_amdgcn_exp2f(-LOG2E * z);
    return __builtin_amdgcn_rcpf(1.0f + p);
}

// Broadcast weight (i) from the lane-distributed register file (compile-time
// reg/lane after unroll): v_readlane_b32 -> SGPR -> scalar operand of v_fma.
#define WQ(i) __int_as_float(__builtin_amdgcn_readlane(__float_as_int(wreg[(i) >> 6]), (i) & 63))

// =================== Phase 1: recurrent h-path (R11 exact, 2.33ms) ==========
// R17 lesson: LDS share beyond ~360 floats regresses — ds_read exposure grows
// nonlinearly (prefetch depth capped by VGPRs; 90 reads/step is the knee).
// Split: LDS = Wh2 rows 0..17 (360 floats); readlane = 852:
//   0..99 Wh1 | 100..149 bh1 | 150..789 Wh2 rows 18..49 | 790..809 bh2
//   | 810..849 Wh3 | 850..851 bh3
__global__ void __launch_bounds__(256, 1)
hpath_kernel(const float* __restrict__ w,
             const float* __restrict__ Wh1, const float* __restrict__ bh1,
             const float* __restrict__ Wh2, const float* __restrict__ bh2,
             const float* __restrict__ Wh3, const float* __restrict__ bh3,
             float2* __restrict__ out, int B, int T)
{
    __shared__ float4 sW2[90];   // Wh2 rows 0..17, row k at [5k..5k+4]
    {
        float* s2 = (float*)sW2;
        for (int i = threadIdx.x; i < 360; i += 256) s2[i] = Wh2[i];
    }

    const int lane = threadIdx.x & 63;
    float wreg[14];
#pragma unroll
    for (int r = 0; r < 14; ++r) {
        const int idx = r * 64 + lane;
        float v = 0.f;
        if      (idx < 100) v = Wh1[idx];
        else if (idx < 150) v = bh1[idx - 100];
        else if (idx < 790) v = Wh2[360 + (idx - 150)];   // rows 18..49
        else if (idx < 810) v = bh2[idx - 790];
        else if (idx < 850) v = Wh3[idx - 810];
        else if (idx < 852) v = bh3[idx - 850];
        wreg[r] = v;
    }
    __syncthreads();

    const int bidx = blockIdx.x * blockDim.x + threadIdx.x;
    if (bidx >= B) return;   // B % 256 == 0: never taken

    float h0 = w[2 * bidx], h1 = w[2 * bidx + 1];
    float2* __restrict__ orow = out + (size_t)bidx * (size_t)T;

    for (int t = 0; t < T; ++t) {
        // ---- 2 -> 50, lrelu (readlane) ----
        float a1[50];
#pragma unroll
        for (int j = 0; j < 50; ++j)
            a1[j] = lrelu(fmaf(h0, WQ(j), fmaf(h1, WQ(50 + j), WQ(100 + j))));

        // ---- 50 -> 20 accumulate ----
        float acc[20];
#pragma unroll
        for (int c = 0; c < 20; ++c) acc[c] = WQ(790 + c);

#pragma unroll
        for (int k = 0; k < 18; ++k) {          // rows 0..17 via LDS
            const float ak = a1[k];
#pragma unroll
            for (int c = 0; c < 5; ++c) {
                const float4 v = sW2[k * 5 + c];
                acc[4*c+0] = fmaf(ak, v.x, acc[4*c+0]);
                acc[4*c+1] = fmaf(ak, v.y, acc[4*c+1]);
                acc[4*c+2] = fmaf(ak, v.z, acc[4*c+2]);
                acc[4*c+3] = fmaf(ak, v.w, acc[4*c+3]);
            }
        }
#pragma unroll
        for (int k = 18; k < 50; ++k) {         // rows 18..49 via readlane
            const float ak = a1[k];
#pragma unroll
            for (int c = 0; c < 20; ++c)
                acc[c] = fmaf(ak, WQ(150 + (k - 18) * 20 + c), acc[c]);
        }

        // ---- 20 -> 2, lrelu ----
        float z0 = WQ(850), z1 = WQ(851);
#pragma unroll
        for (int k = 0; k < 20; ++k) {
            const float a2k = lrelu(acc[k]);
            z0 = fmaf(a2k, WQ(810 + 2 * k + 0), z0);
            z1 = fmaf(a2k, WQ(810 + 2 * k + 1), z1);
        }
        h0 = lrelu(z0); h1 = lrelu(z1);
        orow[t] = make_float2(h0, h1);
    }
}

// =================== Phase 2: x = G(h), in place, 4 points/thread ===========
// R6 body (2.06ms at 1 wave/SIMD, latency-exposed). launch_bounds(256,2):
// VGPR cap 128 — acc[4][20]=80 + ~35 temps fits; R17's (256,3) cap 84 spilled
// (FETCH 6.7GB). 2 waves/SIMD should hide LDS latency: pipe floors are
// VALU 0.62ms / LDS 0.79ms.
__global__ void __launch_bounds__(256, 2)
xpath_kernel(const float* __restrict__ Wx1, const float* __restrict__ bx1,
             const float* __restrict__ Wx2, const float* __restrict__ bx2,
             const float* __restrict__ Wx3, const float* __restrict__ bx3,
             float2* __restrict__ out, int NG)   // NG = NP/4 four-point groups
{
    __shared__ float4 sL1[50];   // (W1[0][k], W1[1][k], b1[k], 0)
    __shared__ float4 sW2[250];  // W2[50][20] row-major; row k at [5k..5k+4]
    __shared__ float4 sW3[10];   // (W3[2q][0], W3[2q][1], W3[2q+1][0], W3[2q+1][1])
    __shared__ float4 sB2[5];
    __shared__ float2 sB3;
    {
        const int tid = threadIdx.x;
        if (tid < 50) sL1[tid] = make_float4(Wx1[tid], Wx1[50 + tid], bx1[tid], 0.f);
        float* s2 = (float*)sW2;
        for (int i = tid; i < 1000; i += 256) s2[i] = Wx2[i];
        if (tid < 40) ((float*)sW3)[tid] = Wx3[tid];
        if (tid < 20) ((float*)sB2)[tid] = bx2[tid];
        if (tid == 0) sB3 = make_float2(bx3[0], bx3[1]);
    }
    __syncthreads();

    const int stride = gridDim.x * blockDim.x;
    for (int g = blockIdx.x * blockDim.x + threadIdx.x; g < NG; g += stride) {
        const float4 hv01 = reinterpret_cast<const float4*>(out)[2 * g];
        const float4 hv23 = reinterpret_cast<const float4*>(out)[2 * g + 1];
        const float h0[4] = {hv01.x, hv01.z, hv23.x, hv23.z};
        const float h1[4] = {hv01.y, hv01.w, hv23.y, hv23.w};

        float acc[4][20];
#pragma unroll
        for (int c4 = 0; c4 < 5; ++c4) {
            const float4 b = sB2[c4];
#pragma unroll
            for (int p = 0; p < 4; ++p) {
                acc[p][4 * c4 + 0] = b.x; acc[p][4 * c4 + 1] = b.y;
                acc[p][4 * c4 + 2] = b.z; acc[p][4 * c4 + 3] = b.w;
            }
        }
        // layers 1+2 fused over k
#pragma unroll
        for (int k = 0; k < 50; ++k) {
            const float4 l1 = sL1[k];
            float xk[4];
#pragma unroll
            for (int p = 0; p < 4; ++p)
                xk[p] = sigf(fmaf(h0[p], l1.x, fmaf(h1[p], l1.y, l1.z)));
#pragma unroll
            for (int c4 = 0; c4 < 5; ++c4) {
                const float4 v = sW2[k * 5 + c4];
#pragma unroll
                for (int p = 0; p < 4; ++p) {
                    acc[p][4 * c4 + 0] = fmaf(xk[p], v.x, acc[p][4 * c4 + 0]);
                    acc[p][4 * c4 + 1] = fmaf(xk[p], v.y, acc[p][4 * c4 + 1]);
                    acc[p][4 * c4 + 2] = fmaf(xk[p], v.z, acc[p][4 * c4 + 2]);
                    acc[p][4 * c4 + 3] = fmaf(xk[p], v.w, acc[p][4 * c4 + 3]);
                }
            }
        }
        // layer 3 (sigmoid of acc fused into the dot)
        const float2 b3 = sB3;
        float z0[4], z1[4];
#pragma unroll
        for (int p = 0; p < 4; ++p) { z0[p] = b3.x; z1[p] = b3.y; }
#pragma unroll
        for (int q = 0; q < 10; ++q) {
            const float4 v = sW3[q];
#pragma unroll
            for (int p = 0; p < 4; ++p) {
                const float x2a = sigf(acc[p][2 * q + 0]);
                const float x2b = sigf(acc[p][2 * q + 1]);
                z0[p] = fmaf(x2a, v.x, z0[p]); z1[p] = fmaf(x2a, v.y, z1[p]);
                z0[p] = fmaf(x2b, v.z, z0[p]); z1[p] = fmaf(x2b, v.w, z1[p]);
            }
        }
        const float4 o01 = make_float4(sigf(z0[0]), sigf(z1[0]), sigf(z0[1]), sigf(z1[1]));
        const float4 o23 = make_float4(sigf(z0[2]), sigf(z1[2]), sigf(z0[3]), sigf(z1[3]));
        reinterpret_cast<float4*>(out)[2 * g]     = o01;
        reinterpret_cast<float4*>(out)[2 * g + 1] = o23;
    }
}

extern "C" void kernel_launch(void* const* d_in, const int* in_sizes, int n_in,
                              void* d_out, int out_size, void* d_ws, size_t ws_size,
                              hipStream_t stream)
{
    const float* w   = (const float*)d_in[0];
    const float* Wh1 = (const float*)d_in[1];
    const float* bh1 = (const float*)d_in[2];
    const float* Wh2 = (const float*)d_in[3];
    const float* bh2 = (const float*)d_in[4];
    const float* Wh3 = (const float*)d_in[5];
    const float* bh3 = (const float*)d_in[6];
    const float* Wx1 = (const float*)d_in[7];
    const float* bx1 = (const float*)d_in[8];
    const float* Wx2 = (const float*)d_in[9];
    const float* bx2 = (const float*)d_in[10];
    const float* Wx3 = (const float*)d_in[11];
    const float* bx3 = (const float*)d_in[12];

    const int B  = in_sizes[0] / 2;        // 65536
    const int T  = out_size / (B * 2);     // 512
    const int NP = B * T;                  // 33.5M (b,t) points; divisible by 4
    const int NG = NP / 4;

    float2* out2 = (float2*)d_out;

    // Phase 1: recurrent h-path (R11 proven split: LDS 360 / readlane 852).
    hpath_kernel<<<(B + 255) / 256, 256, 0, stream>>>(
        w, Wh1, bh1, Wh2, bh2, Wh3, bh3, out2, B, T);

    // Phase 2: x = G(h) in place, 4 points/thread, 2 waves/SIMD.
    xpath_kernel<<<4096, 256, 0, stream>>>(
        Wx1, bx1, Wx2, bx2, Wx3, bx3, out2, NG);
}

// Round 19
// 4203.851 us; speedup vs baseline: 1.5004x; 1.2407x over previous
//
#include <hip/hip_runtime.h>

#define LOG2E 1.44269504088896340736f

__device__ __forceinline__ float lrelu(float z) { return fmaxf(z, 0.01f * z); }
__device__ __forceinline__ float sigf(float z) {
    float p = __builtin_amdgcn_exp2f(-LOG2E * z);
    return __builtin_amdgcn_rcpf(1.0f + p);
}

#define WQ(i) __int_as_float(__builtin_amdgcn_readlane(__float_as_int(wreg[(i) >> 6]), (i) & 63))

// ====== PC-v2: 2 F-waves + 2 X-waves per block, 2 points/thread each ======
// Model (validated R10-R18): readlane 8cyc/float (per-SIMD VALU), uniform
// ds_read_b128 12cyc (per-CU LDS pipe), fma 2cyc, co-resident waves serialize
// VALU. 2pt/thread amortizes every broadcast over 2 points; F and X waves sit
// on different SIMDs (4 waves/block -> round-robin) so their VALU runs in
// parallel, and X reads h via LDS handoff (no HBM h traffic, no second pass).
// Balance: R_h=472, R_x=432 readlane floats; rest via LDS.
//   F pack: 0..99 Wh1 | 100..149 bh1 | 150..409 Wh2 rows 37..49
//           | 410..429 bh2 | 430..469 Wh3 | 470..471 bh3
//   X pack: 0..99 Wx1 | 100..149 bx1 | 150..369 Wx2 rows 39..49
//           | 370..389 bx2 | 390..429 Wx3 | 430..431 bx3
// LDS: Wh2 rows 0..36 (185 f4), Wx2 rows 0..38 (195 f4), hbuf 4KB.
__global__ void __launch_bounds__(256, 1)
pc2_kernel(const float* __restrict__ w,
           const float* __restrict__ Wh1, const float* __restrict__ bh1,
           const float* __restrict__ Wh2, const float* __restrict__ bh2,
           const float* __restrict__ Wh3, const float* __restrict__ bh3,
           const float* __restrict__ Wx1, const float* __restrict__ bx1,
           const float* __restrict__ Wx2, const float* __restrict__ bx2,
           const float* __restrict__ Wx3, const float* __restrict__ bx3,
           float2* __restrict__ out, int B, int T)
{
    __shared__ float4 sW2h[185];       // Wh2 rows 0..36
    __shared__ float4 sW2x[195];       // Wx2 rows 0..38
    __shared__ float2 hbuf[2][256];    // double-buffered h handoff

    {
        float* a = (float*)sW2h;
        for (int i = threadIdx.x; i < 740; i += 256) a[i] = Wh2[i];
        float* b = (float*)sW2x;
        for (int i = threadIdx.x; i < 780; i += 256) b[i] = Wx2[i];
    }

    const int wid  = threadIdx.x >> 6;     // 0..3
    const int lane = threadIdx.x & 63;
    const bool is_f = (wid < 2);

    float wreg[8];
    if (is_f) {
#pragma unroll
        for (int r = 0; r < 8; ++r) {
            const int idx = r * 64 + lane;
            float v = 0.f;
            if      (idx < 100) v = Wh1[idx];
            else if (idx < 150) v = bh1[idx - 100];
            else if (idx < 410) v = Wh2[740 + (idx - 150)];   // rows 37..49
            else if (idx < 430) v = bh2[idx - 410];
            else if (idx < 470) v = Wh3[idx - 430];
            else if (idx < 472) v = bh3[idx - 470];
            wreg[r] = v;
        }
    } else {
#pragma unroll
        for (int r = 0; r < 8; ++r) {
            const int idx = r * 64 + lane;
            float v = 0.f;
            if      (idx < 100) v = Wx1[idx];
            else if (idx < 150) v = bx1[idx - 100];
            else if (idx < 370) v = Wx2[780 + (idx - 150)];   // rows 39..49
            else if (idx < 390) v = bx2[idx - 370];
            else if (idx < 430) v = Wx3[idx - 390];
            else if (idx < 432) v = bx3[idx - 430];
            wreg[r] = v;
        }
    }
    __syncthreads();

    // F-wave w (0,1): points w*128+lane (A) and w*128+64+lane (B) in-block.
    // X-wave w (2,3): same ranges with (w-2).
    const int lw = is_f ? wid : (wid - 2);
    const int lpA = lw * 128 + lane;
    const int lpB = lpA + 64;
    const int pA  = blockIdx.x * 256 + lpA;
    const int pB  = blockIdx.x * 256 + lpB;

    float hA0 = 0.f, hA1 = 0.f, hB0 = 0.f, hB1 = 0.f;
    if (is_f) {
        hA0 = w[2 * pA]; hA1 = w[2 * pA + 1];
        hB0 = w[2 * pB]; hB1 = w[2 * pB + 1];
    }
    float2* __restrict__ orowA = out + (size_t)pA * (size_t)T;
    float2* __restrict__ orowB = out + (size_t)pB * (size_t)T;

    for (int t = 0; t <= T; ++t) {
        if (is_f) {
            if (t < T) {
                // ===== F: both chains, broadcasts shared =====
                float a1A[50], a1B[50];
#pragma unroll
                for (int j = 0; j < 50; ++j) {
                    const float s0 = WQ(j), s1 = WQ(50 + j), sb = WQ(100 + j);
                    a1A[j] = lrelu(fmaf(hA0, s0, fmaf(hA1, s1, sb)));
                    a1B[j] = lrelu(fmaf(hB0, s0, fmaf(hB1, s1, sb)));
                }
                float accA[20], accB[20];
#pragma unroll
                for (int c = 0; c < 20; ++c) {
                    const float bv = WQ(410 + c);
                    accA[c] = bv; accB[c] = bv;
                }
#pragma unroll
                for (int k = 0; k < 37; ++k) {          // rows 0..36 via LDS
                    const float akA = a1A[k], akB = a1B[k];
#pragma unroll
                    for (int c = 0; c < 5; ++c) {
                        const float4 v = sW2h[k * 5 + c];
                        accA[4*c+0] = fmaf(akA, v.x, accA[4*c+0]);
                        accA[4*c+1] = fmaf(akA, v.y, accA[4*c+1]);
                        accA[4*c+2] = fmaf(akA, v.z, accA[4*c+2]);
                        accA[4*c+3] = fmaf(akA, v.w, accA[4*c+3]);
                        accB[4*c+0] = fmaf(akB, v.x, accB[4*c+0]);
                        accB[4*c+1] = fmaf(akB, v.y, accB[4*c+1]);
                        accB[4*c+2] = fmaf(akB, v.z, accB[4*c+2]);
                        accB[4*c+3] = fmaf(akB, v.w, accB[4*c+3]);
                    }
                }
#pragma unroll
                for (int k = 37; k < 50; ++k) {         // rows 37..49 readlane
                    const float akA = a1A[k], akB = a1B[k];
#pragma unroll
                    for (int c = 0; c < 20; ++c) {
                        const float wv = WQ(150 + (k - 37) * 20 + c);
                        accA[c] = fmaf(akA, wv, accA[c]);
                        accB[c] = fmaf(akB, wv, accB[c]);
                    }
                }
                float zA0 = WQ(470), zA1 = WQ(471);
                float zB0 = zA0, zB1 = zA1;
#pragma unroll
                for (int k = 0; k < 20; ++k) {
                    const float wx = WQ(430 + 2 * k), wy = WQ(431 + 2 * k);
                    const float eA = lrelu(accA[k]), eB = lrelu(accB[k]);
                    zA0 = fmaf(eA, wx, zA0); zA1 = fmaf(eA, wy, zA1);
                    zB0 = fmaf(eB, wx, zB0); zB1 = fmaf(eB, wy, zB1);
                }
                hA0 = lrelu(zA0); hA1 = lrelu(zA1);
                hB0 = lrelu(zB0); hB1 = lrelu(zB1);

                hbuf[t & 1][lpA] = make_float2(hA0, hA1);
                hbuf[t & 1][lpB] = make_float2(hB0, hB1);
            }
        } else {
            if (t > 0) {
                // ===== X: x_s = sig3(h_s), s = t-1, both points =====
                const int s = t - 1;
                const float2 hvA = hbuf[s & 1][lpA];
                const float2 hvB = hbuf[s & 1][lpB];

                float accA[20], accB[20];
#pragma unroll
                for (int c = 0; c < 20; ++c) {
                    const float bv = WQ(370 + c);
                    accA[c] = bv; accB[c] = bv;
                }
#pragma unroll
                for (int k = 0; k < 50; ++k) {
                    const float s0 = WQ(k), s1 = WQ(50 + k), sb = WQ(100 + k);
                    const float xkA = sigf(fmaf(hvA.x, s0, fmaf(hvA.y, s1, sb)));
                    const float xkB = sigf(fmaf(hvB.x, s0, fmaf(hvB.y, s1, sb)));
                    if (k < 39) {                        // rows 0..38 via LDS
#pragma unroll
                        for (int c = 0; c < 5; ++c) {
                            const float4 v = sW2x[k * 5 + c];
                            accA[4*c+0] = fmaf(xkA, v.x, accA[4*c+0]);
                            accA[4*c+1] = fmaf(xkA, v.y, accA[4*c+1]);
                            accA[4*c+2] = fmaf(xkA, v.z, accA[4*c+2]);
                            accA[4*c+3] = fmaf(xkA, v.w, accA[4*c+3]);
                            accB[4*c+0] = fmaf(xkB, v.x, accB[4*c+0]);
                            accB[4*c+1] = fmaf(xkB, v.y, accB[4*c+1]);
                            accB[4*c+2] = fmaf(xkB, v.z, accB[4*c+2]);
                            accB[4*c+3] = fmaf(xkB, v.w, accB[4*c+3]);
                        }
                    } else {                             // rows 39..49 readlane
#pragma unroll
                        for (int c = 0; c < 20; ++c) {
                            const float wv = WQ(150 + (k - 39) * 20 + c);
                            accA[c] = fmaf(xkA, wv, accA[c]);
                            accB[c] = fmaf(xkB, wv, accB[c]);
                        }
                    }
                }
                float zA0 = WQ(430), zA1 = WQ(431);
                float zB0 = zA0, zB1 = zA1;
#pragma unroll
                for (int k = 0; k < 20; ++k) {
                    const float wx = WQ(390 + 2 * k), wy = WQ(391 + 2 * k);
                    const float eA = sigf(accA[k]), eB = sigf(accB[k]);
                    zA0 = fmaf(eA, wx, zA0); zA1 = fmaf(eA, wy, zA1);
                    zB0 = fmaf(eB, wx, zB0); zB1 = fmaf(eB, wy, zB1);
                }
                orowA[s] = make_float2(sigf(zA0), sigf(zA1));
                orowB[s] = make_float2(sigf(zB0), sigf(zB1));
            }
        }
        __syncthreads();   // orders hbuf write (iter t) -> read (iter t+1)
    }
}

extern "C" void kernel_launch(void* const* d_in, const int* in_sizes, int n_in,
                              void* d_out, int out_size, void* d_ws, size_t ws_size,
                              hipStream_t stream)
{
    const float* w   = (const float*)d_in[0];
    const float* Wh1 = (const float*)d_in[1];
    const float* bh1 = (const float*)d_in[2];
    const float* Wh2 = (const float*)d_in[3];
    const float* bh2 = (const float*)d_in[4];
    const float* Wh3 = (const float*)d_in[5];
    const float* bh3 = (const float*)d_in[6];
    const float* Wx1 = (const float*)d_in[7];
    const float* bx1 = (const float*)d_in[8];
    const float* Wx2 = (const float*)d_in[9];
    const float* bx2 = (const float*)d_in[10];
    const float* Wx3 = (const float*)d_in[11];
    const float* bx3 = (const float*)d_in[12];

    const int B = in_sizes[0] / 2;        // 65536 (divisible by 256)
    const int T = out_size / (B * 2);     // 512

    // 256 points/block: waves 0,1 = F @2pt/thread; waves 2,3 = X @2pt/thread.
    pc2_kernel<<<B / 256, 256, 0, stream>>>(
        w, Wh1, bh1, Wh2, bh2, Wh3, bh3,
        Wx1, bx1, Wx2, bx2, Wx3, bx3,
        (float2*)d_out, B, T);
}

// Round 21
// 4019.540 us; speedup vs baseline: 1.5692x; 1.0459x over previous
//
#include <hip/hip_runtime.h>

#define LOG2E 1.44269504088896340736f

__device__ __forceinline__ float lrelu(float z) { return fmaxf(z, 0.01f * z); }
__device__ __forceinline__ float sigf(float z) {
    float p = __builtin_amdgcn_exp2f(-LOG2E * z);
    return __builtin_amdgcn_rcpf(1.0f + p);
}

#define WQ(i) __int_as_float(__builtin_amdgcn_readlane(__float_as_int(wreg[(i) >> 6]), (i) & 63))

// ====== PC-v3: R19 + explicit double-buffered LDS row prefetch ======
// R19 evidence: VGPR_Count=48 -> compiler allocated no prefetch depth; each
// of the ~380 ds_read_b128/step exposed ~64cyc latency serially at 1 wave/
// SIMD (step 20.5K cyc vs 9.2K pipe model; total conserved vs R11). Fix:
// preload LDS row k+1 into named float4 temps (compile-time indices after
// full unroll) while row k's 40 fma execute -> latency overlapped, VGPR
// forced up. Structure/packing identical to R19:
//   F pack: 0..99 Wh1 | 100..149 bh1 | 150..409 Wh2 rows 37..49
//           | 410..429 bh2 | 430..469 Wh3 | 470..471 bh3
//   X pack: 0..99 Wx1 | 100..149 bx1 | 150..369 Wx2 rows 39..49
//           | 370..389 bx2 | 390..429 Wx3 | 430..431 bx3
// LDS: Wh2 rows 0..36 (185 f4), Wx2 rows 0..38 (195 f4), hbuf 4KB.
__global__ void __launch_bounds__(256, 1)
pc3_kernel(const float* __restrict__ w,
           const float* __restrict__ Wh1, const float* __restrict__ bh1,
           const float* __restrict__ Wh2, const float* __restrict__ bh2,
           const float* __restrict__ Wh3, const float* __restrict__ bh3,
           const float* __restrict__ Wx1, const float* __restrict__ bx1,
           const float* __restrict__ Wx2, const float* __restrict__ bx2,
           const float* __restrict__ Wx3, const float* __restrict__ bx3,
           float2* __restrict__ out, int B, int T)
{
    __shared__ float4 sW2h[185];       // Wh2 rows 0..36
    __shared__ float4 sW2x[195];       // Wx2 rows 0..38
    __shared__ float2 hbuf[2][256];    // double-buffered h handoff

    {
        float* a = (float*)sW2h;
        for (int i = threadIdx.x; i < 740; i += 256) a[i] = Wh2[i];
        float* b = (float*)sW2x;
        for (int i = threadIdx.x; i < 780; i += 256) b[i] = Wx2[i];
    }

    const int wid  = threadIdx.x >> 6;     // 0..3
    const int lane = threadIdx.x & 63;
    const bool is_f = (wid < 2);

    float wreg[8];
    if (is_f) {
#pragma unroll
        for (int r = 0; r < 8; ++r) {
            const int idx = r * 64 + lane;
            float v = 0.f;
            if      (idx < 100) v = Wh1[idx];
            else if (idx < 150) v = bh1[idx - 100];
            else if (idx < 410) v = Wh2[740 + (idx - 150)];   // rows 37..49
            else if (idx < 430) v = bh2[idx - 410];
            else if (idx < 470) v = Wh3[idx - 430];
            else if (idx < 472) v = bh3[idx - 470];
            wreg[r] = v;
        }
    } else {
#pragma unroll
        for (int r = 0; r < 8; ++r) {
            const int idx = r * 64 + lane;
            float v = 0.f;
            if      (idx < 100) v = Wx1[idx];
            else if (idx < 150) v = bx1[idx - 100];
            else if (idx < 370) v = Wx2[780 + (idx - 150)];   // rows 39..49
            else if (idx < 390) v = bx2[idx - 370];
            else if (idx < 430) v = Wx3[idx - 390];
            else if (idx < 432) v = bx3[idx - 430];
            wreg[r] = v;
        }
    }
    __syncthreads();

    const int lw = is_f ? wid : (wid - 2);
    const int lpA = lw * 128 + lane;
    const int lpB = lpA + 64;
    const int pA  = blockIdx.x * 256 + lpA;
    const int pB  = blockIdx.x * 256 + lpB;

    float hA0 = 0.f, hA1 = 0.f, hB0 = 0.f, hB1 = 0.f;
    if (is_f) {
        hA0 = w[2 * pA]; hA1 = w[2 * pA + 1];
        hB0 = w[2 * pB]; hB1 = w[2 * pB + 1];
    }
    float2* __restrict__ orowA = out + (size_t)pA * (size_t)T;
    float2* __restrict__ orowB = out + (size_t)pB * (size_t)T;

    for (int t = 0; t <= T; ++t) {
        if (is_f) {
            if (t < T) {
                // ===== F: both chains, broadcasts shared =====
                float a1A[50], a1B[50];
#pragma unroll
                for (int j = 0; j < 50; ++j) {
                    const float s0 = WQ(j), s1 = WQ(50 + j), sb = WQ(100 + j);
                    a1A[j] = lrelu(fmaf(hA0, s0, fmaf(hA1, s1, sb)));
                    a1B[j] = lrelu(fmaf(hB0, s0, fmaf(hB1, s1, sb)));
                }
                float accA[20], accB[20];
#pragma unroll
                for (int c = 0; c < 20; ++c) {
                    const float bv = WQ(410 + c);
                    accA[c] = bv; accB[c] = bv;
                }
                // rows 0..36 via LDS with 1-row double-buffer prefetch
                float4 pb[2][5];
#pragma unroll
                for (int c = 0; c < 5; ++c) pb[0][c] = sW2h[c];
#pragma unroll
                for (int k = 0; k < 37; ++k) {
                    const int cur = k & 1, nxt = cur ^ 1;
                    if (k + 1 < 37) {
#pragma unroll
                        for (int c = 0; c < 5; ++c)
                            pb[nxt][c] = sW2h[(k + 1) * 5 + c];
                    }
                    const float akA = a1A[k], akB = a1B[k];
#pragma unroll
                    for (int c = 0; c < 5; ++c) {
                        const float4 v = pb[cur][c];
                        accA[4*c+0] = fmaf(akA, v.x, accA[4*c+0]);
                        accA[4*c+1] = fmaf(akA, v.y, accA[4*c+1]);
                        accA[4*c+2] = fmaf(akA, v.z, accA[4*c+2]);
                        accA[4*c+3] = fmaf(akA, v.w, accA[4*c+3]);
                        accB[4*c+0] = fmaf(akB, v.x, accB[4*c+0]);
                        accB[4*c+1] = fmaf(akB, v.y, accB[4*c+1]);
                        accB[4*c+2] = fmaf(akB, v.z, accB[4*c+2]);
                        accB[4*c+3] = fmaf(akB, v.w, accB[4*c+3]);
                    }
                }
#pragma unroll
                for (int k = 37; k < 50; ++k) {         // rows 37..49 readlane
                    const float akA = a1A[k], akB = a1B[k];
#pragma unroll
                    for (int c = 0; c < 20; ++c) {
                        const float wv = WQ(150 + (k - 37) * 20 + c);
                        accA[c] = fmaf(akA, wv, accA[c]);
                        accB[c] = fmaf(akB, wv, accB[c]);
                    }
                }
                float zA0 = WQ(470), zA1 = WQ(471);
                float zB0 = zA0, zB1 = zA1;
#pragma unroll
                for (int k = 0; k < 20; ++k) {
                    const float wx = WQ(430 + 2 * k), wy = WQ(431 + 2 * k);
                    const float eA = lrelu(accA[k]), eB = lrelu(accB[k]);
                    zA0 = fmaf(eA, wx, zA0); zA1 = fmaf(eA, wy, zA1);
                    zB0 = fmaf(eB, wx, zB0); zB1 = fmaf(eB, wy, zB1);
                }
                hA0 = lrelu(zA0); hA1 = lrelu(zA1);
                hB0 = lrelu(zB0); hB1 = lrelu(zB1);

                hbuf[t & 1][lpA] = make_float2(hA0, hA1);
                hbuf[t & 1][lpB] = make_float2(hB0, hB1);
            }
        } else {
            if (t > 0) {
                // ===== X: x_s = sig3(h_s), s = t-1, both points =====
                const int s = t - 1;
                const float2 hvA = hbuf[s & 1][lpA];
                const float2 hvB = hbuf[s & 1][lpB];

                float accA[20], accB[20];
#pragma unroll
                for (int c = 0; c < 20; ++c) {
                    const float bv = WQ(370 + c);
                    accA[c] = bv; accB[c] = bv;
                }
                // k<39: LDS rows with 1-row double-buffer prefetch
                float4 pb[2][5];
#pragma unroll
                for (int c = 0; c < 5; ++c) pb[0][c] = sW2x[c];
#pragma unroll
                for (int k = 0; k < 50; ++k) {
                    const float s0 = WQ(k), s1 = WQ(50 + k), sb = WQ(100 + k);
                    const float xkA = sigf(fmaf(hvA.x, s0, fmaf(hvA.y, s1, sb)));
                    const float xkB = sigf(fmaf(hvB.x, s0, fmaf(hvB.y, s1, sb)));
                    if (k < 39) {
                        const int cur = k & 1, nxt = cur ^ 1;
                        if (k + 1 < 39) {
#pragma unroll
                            for (int c = 0; c < 5; ++c)
                                pb[nxt][c] = sW2x[(k + 1) * 5 + c];
                        }
#pragma unroll
                        for (int c = 0; c < 5; ++c) {
                            const float4 v = pb[cur][c];
                            accA[4*c+0] = fmaf(xkA, v.x, accA[4*c+0]);
                            accA[4*c+1] = fmaf(xkA, v.y, accA[4*c+1]);
                            accA[4*c+2] = fmaf(xkA, v.z, accA[4*c+2]);
                            accA[4*c+3] = fmaf(xkA, v.w, accA[4*c+3]);
                            accB[4*c+0] = fmaf(xkB, v.x, accB[4*c+0]);
                            accB[4*c+1] = fmaf(xkB, v.y, accB[4*c+1]);
                            accB[4*c+2] = fmaf(xkB, v.z, accB[4*c+2]);
                            accB[4*c+3] = fmaf(xkB, v.w, accB[4*c+3]);
                        }
                    } else {                             // rows 39..49 readlane
#pragma unroll
                        for (int c = 0; c < 20; ++c) {
                            const float wv = WQ(150 + (k - 39) * 20 + c);
                            accA[c] = fmaf(xkA, wv, accA[c]);
                            accB[c] = fmaf(xkB, wv, accB[c]);
                        }
                    }
                }
                float zA0 = WQ(430), zA1 = WQ(431);
                float zB0 = zA0, zB1 = zA1;
#pragma unroll
                for (int k = 0; k < 20; ++k) {
                    const float wx = WQ(390 + 2 * k), wy = WQ(391 + 2 * k);
                    const float eA = sigf(accA[k]), eB = sigf(accB[k]);
                    zA0 = fmaf(eA, wx, zA0); zA1 = fmaf(eA, wy, zA1);
                    zB0 = fmaf(eB, wx, zB0); zB1 = fmaf(eB, wy, zB1);
                }
                orowA[s] = make_float2(sigf(zA0), sigf(zA1));
                orowB[s] = make_float2(sigf(zB0), sigf(zB1));
            }
        }
        __syncthreads();   // orders hbuf write (iter t) -> read (iter t+1)
    }
}

extern "C" void kernel_launch(void* const* d_in, const int* in_sizes, int n_in,
                              void* d_out, int out_size, void* d_ws, size_t ws_size,
                              hipStream_t stream)
{
    const float* w   = (const float*)d_in[0];
    const float* Wh1 = (const float*)d_in[1];
    const float* bh1 = (const float*)d_in[2];
    const float* Wh2 = (const float*)d_in[3];
    const float* bh2 = (const float*)d_in[4];
    const float* Wh3 = (const float*)d_in[5];
    const float* bh3 = (const float*)d_in[6];
    const float* Wx1 = (const float*)d_in[7];
    const float* bx1 = (const float*)d_in[8];
    const float* Wx2 = (const float*)d_in[9];
    const float* bx2 = (const float*)d_in[10];
    const float* Wx3 = (const float*)d_in[11];
    const float* bx3 = (const float*)d_in[12];

    const int B = in_sizes[0] / 2;        // 65536 (divisible by 256)
    const int T = out_size / (B * 2);     // 512

    pc3_kernel<<<B / 256, 256, 0, stream>>>(
        w, Wh1, bh1, Wh2, bh2, Wh3, bh3,
        Wx1, bx1, Wx2, bx2, Wx3, bx3,
        (float2*)d_out, B, T);
}

// Round 23
// 4005.341 us; speedup vs baseline: 1.5748x; 1.0035x over previous
//
#include <hip/hip_runtime.h>

#define LOG2E 1.44269504088896340736f

__device__ __forceinline__ float lrelu(float z) { return fmaxf(z, 0.01f * z); }
__device__ __forceinline__ float sigf(float z) {
    float p = __builtin_amdgcn_exp2f(-LOG2E * z);
    return __builtin_amdgcn_rcpf(1.0f + p);
}

#define WQ(i) __int_as_float(__builtin_amdgcn_readlane(__float_as_int(wreg[(i) >> 6]), (i) & 63))

// ====== PC-v4: PC-v3 + sched_group_barrier-pinned LDS prefetch ======
// R21 evidence: explicit pb[2][5] double-buffer collapsed by the compiler
// (VGPR stayed 48; ds_reads re-sunk next to uses; step 19.8K cyc vs 10K
// model = ~380 reads x ~25cyc exposed). Fix: pin emission order with
// __builtin_amdgcn_sched_group_barrier — per k: 5 DS_READ (row k+1), then
// 40 VALU (row k consume). Row latency then hides under the previous row's
// 80cyc of FMA. SGB is scheduling-only (correctness-safe). Diagnostic:
// VGPR>=88 if honored. Structure/packing identical to R19/R21.
__global__ void __launch_bounds__(256, 1)
pc4_kernel(const float* __restrict__ w,
           const float* __restrict__ Wh1, const float* __restrict__ bh1,
           const float* __restrict__ Wh2, const float* __restrict__ bh2,
           const float* __restrict__ Wh3, const float* __restrict__ bh3,
           const float* __restrict__ Wx1, const float* __restrict__ bx1,
           const float* __restrict__ Wx2, const float* __restrict__ bx2,
           const float* __restrict__ Wx3, const float* __restrict__ bx3,
           float2* __restrict__ out, int B, int T)
{
    __shared__ float4 sW2h[185];       // Wh2 rows 0..36
    __shared__ float4 sW2x[195];       // Wx2 rows 0..38
    __shared__ float2 hbuf[2][256];    // double-buffered h handoff

    {
        float* a = (float*)sW2h;
        for (int i = threadIdx.x; i < 740; i += 256) a[i] = Wh2[i];
        float* b = (float*)sW2x;
        for (int i = threadIdx.x; i < 780; i += 256) b[i] = Wx2[i];
    }

    const int wid  = threadIdx.x >> 6;     // 0..3
    const int lane = threadIdx.x & 63;
    const bool is_f = (wid < 2);

    float wreg[8];
    if (is_f) {
#pragma unroll
        for (int r = 0; r < 8; ++r) {
            const int idx = r * 64 + lane;
            float v = 0.f;
            if      (idx < 100) v = Wh1[idx];
            else if (idx < 150) v = bh1[idx - 100];
            else if (idx < 410) v = Wh2[740 + (idx - 150)];   // rows 37..49
            else if (idx < 430) v = bh2[idx - 410];
            else if (idx < 470) v = Wh3[idx - 430];
            else if (idx < 472) v = bh3[idx - 470];
            wreg[r] = v;
        }
    } else {
#pragma unroll
        for (int r = 0; r < 8; ++r) {
            const int idx = r * 64 + lane;
            float v = 0.f;
            if      (idx < 100) v = Wx1[idx];
            else if (idx < 150) v = bx1[idx - 100];
            else if (idx < 370) v = Wx2[780 + (idx - 150)];   // rows 39..49
            else if (idx < 390) v = bx2[idx - 370];
            else if (idx < 430) v = Wx3[idx - 390];
            else if (idx < 432) v = bx3[idx - 430];
            wreg[r] = v;
        }
    }
    __syncthreads();

    const int lw = is_f ? wid : (wid - 2);
    const int lpA = lw * 128 + lane;
    const int lpB = lpA + 64;
    const int pA  = blockIdx.x * 256 + lpA;
    const int pB  = blockIdx.x * 256 + lpB;

    float hA0 = 0.f, hA1 = 0.f, hB0 = 0.f, hB1 = 0.f;
    if (is_f) {
        hA0 = w[2 * pA]; hA1 = w[2 * pA + 1];
        hB0 = w[2 * pB]; hB1 = w[2 * pB + 1];
    }
    float2* __restrict__ orowA = out + (size_t)pA * (size_t)T;
    float2* __restrict__ orowB = out + (size_t)pB * (size_t)T;

    for (int t = 0; t <= T; ++t) {
        if (is_f) {
            if (t < T) {
                // ===== F: both chains, broadcasts shared =====
                float a1A[50], a1B[50];
#pragma unroll
                for (int j = 0; j < 50; ++j) {
                    const float s0 = WQ(j), s1 = WQ(50 + j), sb = WQ(100 + j);
                    a1A[j] = lrelu(fmaf(hA0, s0, fmaf(hA1, s1, sb)));
                    a1B[j] = lrelu(fmaf(hB0, s0, fmaf(hB1, s1, sb)));
                }
                float accA[20], accB[20];
#pragma unroll
                for (int c = 0; c < 20; ++c) {
                    const float bv = WQ(410 + c);
                    accA[c] = bv; accB[c] = bv;
                }
                // rows 0..36 via LDS; emission pinned: 5 DS_READ then 40 VALU
                float4 pb[2][5];
#pragma unroll
                for (int c = 0; c < 5; ++c) pb[0][c] = sW2h[c];
                __builtin_amdgcn_sched_group_barrier(0x100, 5, 0);  // row 0 reads
#pragma unroll
                for (int k = 0; k < 37; ++k) {
                    const int cur = k & 1, nxt = cur ^ 1;
                    if (k + 1 < 37) {
#pragma unroll
                        for (int c = 0; c < 5; ++c)
                            pb[nxt][c] = sW2h[(k + 1) * 5 + c];
                    }
                    const float akA = a1A[k], akB = a1B[k];
#pragma unroll
                    for (int c = 0; c < 5; ++c) {
                        const float4 v = pb[cur][c];
                        accA[4*c+0] = fmaf(akA, v.x, accA[4*c+0]);
                        accA[4*c+1] = fmaf(akA, v.y, accA[4*c+1]);
                        accA[4*c+2] = fmaf(akA, v.z, accA[4*c+2]);
                        accA[4*c+3] = fmaf(akA, v.w, accA[4*c+3]);
                        accB[4*c+0] = fmaf(akB, v.x, accB[4*c+0]);
                        accB[4*c+1] = fmaf(akB, v.y, accB[4*c+1]);
                        accB[4*c+2] = fmaf(akB, v.z, accB[4*c+2]);
                        accB[4*c+3] = fmaf(akB, v.w, accB[4*c+3]);
                    }
                    if (k + 1 < 37)
                        __builtin_amdgcn_sched_group_barrier(0x100, 5, 0); // next row
                    __builtin_amdgcn_sched_group_barrier(0x002, 40, 0);    // this row's fma
                }
#pragma unroll
                for (int k = 37; k < 50; ++k) {         // rows 37..49 readlane
                    const float akA = a1A[k], akB = a1B[k];
#pragma unroll
                    for (int c = 0; c < 20; ++c) {
                        const float wv = WQ(150 + (k - 37) * 20 + c);
                        accA[c] = fmaf(akA, wv, accA[c]);
                        accB[c] = fmaf(akB, wv, accB[c]);
                    }
                }
                float zA0 = WQ(470), zA1 = WQ(471);
                float zB0 = zA0, zB1 = zA1;
#pragma unroll
                for (int k = 0; k < 20; ++k) {
                    const float wx = WQ(430 + 2 * k), wy = WQ(431 + 2 * k);
                    const float eA = lrelu(accA[k]), eB = lrelu(accB[k]);
                    zA0 = fmaf(eA, wx, zA0); zA1 = fmaf(eA, wy, zA1);
                    zB0 = fmaf(eB, wx, zB0); zB1 = fmaf(eB, wy, zB1);
                }
                hA0 = lrelu(zA0); hA1 = lrelu(zA1);
                hB0 = lrelu(zB0); hB1 = lrelu(zB1);

                hbuf[t & 1][lpA] = make_float2(hA0, hA1);
                hbuf[t & 1][lpB] = make_float2(hB0, hB1);
            }
        } else {
            if (t > 0) {
                // ===== X: x_s = sig3(h_s), s = t-1, both points =====
                const int s = t - 1;
                const float2 hvA = hbuf[s & 1][lpA];
                const float2 hvB = hbuf[s & 1][lpB];

                float accA[20], accB[20];
#pragma unroll
                for (int c = 0; c < 20; ++c) {
                    const float bv = WQ(370 + c);
                    accA[c] = bv; accB[c] = bv;
                }
                float4 pb[2][5];
#pragma unroll
                for (int c = 0; c < 5; ++c) pb[0][c] = sW2x[c];
                __builtin_amdgcn_sched_group_barrier(0x100, 5, 0);  // row 0 reads
#pragma unroll
                for (int k = 0; k < 50; ++k) {
                    const float s0 = WQ(k), s1 = WQ(50 + k), sb = WQ(100 + k);
                    const float xkA = sigf(fmaf(hvA.x, s0, fmaf(hvA.y, s1, sb)));
                    const float xkB = sigf(fmaf(hvB.x, s0, fmaf(hvB.y, s1, sb)));
                    if (k < 39) {
                        const int cur = k & 1, nxt = cur ^ 1;
                        if (k + 1 < 39) {
#pragma unroll
                            for (int c = 0; c < 5; ++c)
                                pb[nxt][c] = sW2x[(k + 1) * 5 + c];
                        }
#pragma unroll
                        for (int c = 0; c < 5; ++c) {
                            const float4 v = pb[cur][c];
                            accA[4*c+0] = fmaf(xkA, v.x, accA[4*c+0]);
                            accA[4*c+1] = fmaf(xkA, v.y, accA[4*c+1]);
                            accA[4*c+2] = fmaf(xkA, v.z, accA[4*c+2]);
                            accA[4*c+3] = fmaf(xkA, v.w, accA[4*c+3]);
                            accB[4*c+0] = fmaf(xkB, v.x, accB[4*c+0]);
                            accB[4*c+1] = fmaf(xkB, v.y, accB[4*c+1]);
                            accB[4*c+2] = fmaf(xkB, v.z, accB[4*c+2]);
                            accB[4*c+3] = fmaf(xkB, v.w, accB[4*c+3]);
                        }
                        if (k + 1 < 39)
                            __builtin_amdgcn_sched_group_barrier(0x100, 5, 0);
                        __builtin_amdgcn_sched_group_barrier(0x002, 40, 0);
                    } else {                             // rows 39..49 readlane
#pragma unroll
                        for (int c = 0; c < 20; ++c) {
                            const float wv = WQ(150 + (k - 39) * 20 + c);
                            accA[c] = fmaf(xkA, wv, accA[c]);
                            accB[c] = fmaf(xkB, wv, accB[c]);
                        }
                    }
                }
                float zA0 = WQ(430), zA1 = WQ(431);
                float zB0 = zA0, zB1 = zA1;
#pragma unroll
                for (int k = 0; k < 20; ++k) {
                    const float wx = WQ(390 + 2 * k), wy = WQ(391 + 2 * k);
                    const float eA = sigf(accA[k]), eB = sigf(accB[k]);
                    zA0 = fmaf(eA, wx, zA0); zA1 = fmaf(eA, wy, zA1);
                    zB0 = fmaf(eB, wx, zB0); zB1 = fmaf(eB, wy, zB1);
                }
                orowA[s] = make_float2(sigf(zA0), sigf(zA1));
                orowB[s] = make_float2(sigf(zB0), sigf(zB1));
            }
        }
        __syncthreads();   // orders hbuf write (iter t) -> read (iter t+1)
    }
}

extern "C" void kernel_launch(void* const* d_in, const int* in_sizes, int n_in,
                              void* d_out, int out_size, void* d_ws, size_t ws_size,
                              hipStream_t stream)
{
    const float* w   = (const float*)d_in[0];
    const float* Wh1 = (const float*)d_in[1];
    const float* bh1 = (const float*)d_in[2];
    const float* Wh2 = (const float*)d_in[3];
    const float* bh2 = (const float*)d_in[4];
    const float* Wh3 = (const float*)d_in[5];
    const float* bh3 = (const float*)d_in[6];
    const float* Wx1 = (const float*)d_in[7];
    const float* bx1 = (const float*)d_in[8];
    const float* Wx2 = (const float*)d_in[9];
    const float* bx2 = (const float*)d_in[10];
    const float* Wx3 = (const float*)d_in[11];
    const float* bx3 = (const float*)d_in[12];

    const int B = in_sizes[0] / 2;        // 65536 (divisible by 256)
    const int T = out_size / (B * 2);     // 512

    pc4_kernel<<<B / 256, 256, 0, stream>>>(
        w, Wh1, bh1, Wh2, bh2, Wh3, bh3,
        Wx1, bx1, Wx2, bx2, Wx3, bx3,
        (float2*)d_out, B, T);
}